// Round 8
// baseline (519.466 us; speedup 1.0000x reference)
//
#include <hip/hip_runtime.h>

typedef __attribute__((ext_vector_type(8))) short bf16x8;
typedef __attribute__((ext_vector_type(4))) float f32x4;
typedef __attribute__((ext_vector_type(4))) int i32x4;
typedef __attribute__((ext_vector_type(4))) unsigned short u16x4;
typedef __attribute__((ext_vector_type(8))) unsigned short u16x8;

#define KDIM 256
#define HWSZ 4096
#define NOUT 765
#define NOUTP 768
#define UPB1 4                                   // k1: 32-px units per block
#define TBYTES ((size_t)16 * NOUTP * HWSZ * 2)   // 100,663,296 B bf16 t-buffer

// Anchors in PIXEL units: w_a = ANCHORS/16 (grid units) and every use multiplies
// by STRIDE=16, so pixel units are exact. Index 9 = dummy for padded o.
__constant__ float c_AW[10] = {10.f,16.f,33.f,30.f,62.f,59.f,116.f,156.f,373.f,0.f};
__constant__ float c_AH[10] = {13.f,30.f,23.f,61.f,45.f,119.f,90.f,198.f,326.f,0.f};

__device__ __forceinline__ unsigned short f2bf(float f) {
  unsigned u = __builtin_bit_cast(unsigned, f);
  u += 0x7fffu + ((u >> 16) & 1u);   // RNE
  return (unsigned short)(u >> 16);
}
__device__ __forceinline__ float bf2f(unsigned short h) {
  return __builtin_bit_cast(float, ((unsigned)h) << 16);
}
__device__ __forceinline__ float sigf(float t) {
  return 1.0f / (1.0f + __expf(-t));
}

// LDS-hazard-only barrier (validated rounds 5-7: correct, absmax stable).
// Does NOT drain vmcnt: prefetch loads + t/out store streams stay in flight.
__device__ __forceinline__ void bar_lds() {
  asm volatile("s_waitcnt lgkmcnt(0)" ::: "memory");
  __builtin_amdgcn_s_barrier();
  __builtin_amdgcn_sched_barrier(0);
}

// ---- prep: conv_w (765x256 f32) -> padded bf16 (768x256), rows 765..767 = 0
__global__ void prep_w(const float* __restrict__ cw, unsigned short* __restrict__ wbf) {
  int e = (blockIdx.x * 256 + threadIdx.x) * 4;
  int o = e >> 8, col = e & 255;
  f32x4 v = {0.f, 0.f, 0.f, 0.f};
  if (o < NOUT) v = *reinterpret_cast<const f32x4*>(cw + o * KDIM + col);
  u16x4 u = { f2bf(v.x), f2bf(v.y), f2bf(v.z), f2bf(v.w) };
  *reinterpret_cast<u16x4*>(wbf + e) = u;
}

// ================= K1 v2: pipelined GEMM =================
// 512 persistent blocks x 4 units; unit = (b, half-row) = 32px x all 768 o.
// 8 waves, wave wv owns o in [96wv, 96wv+96): acc[6][2] = 48 VGPR (r4 measured
// this shape at 112 VGPR total -> 2 blocks/CU). Per unit: issue next unit's 16
// X-loads to regs -> GEMM from xT[cur] -> bias+bf16-pack+store t -> cvt+ds_write
// xT[next] -> bar_lds. One barrier per unit; loads/stores fly across it.
__global__ __launch_bounds__(512) void k1_gemm(
    const float* __restrict__ xin,
    const unsigned short* __restrict__ wbf,
    const float* __restrict__ bias,
    unsigned short* __restrict__ t)
{
  __shared__ __align__(16) unsigned short xT[2][32 * 256];  // 2 x 16 KB, k-bits 3..5 XOR-swizzled by px&7

  const int tid  = threadIdx.x;
  const int lane = tid & 63;
  const int wv   = tid >> 6;
  const int g    = lane >> 4;
  const int r16  = lane & 15;
  const int obase = wv * 96;

  const int u0 = blockIdx.x * UPB1;            // half-row units, 2048 total
  const int b  = u0 >> 7;                      // 4 | 128 -> same b for whole block

  // staging map: thread = (px = tid&31, 16 c's from chunk ck = tid>>5)
  const int spx = tid & 31;
  const int sck = tid >> 5;                    // 0..15
  const int ssw = (spx & 7) << 3;
  const int se0 = spx * 256 + ((sck * 16) ^ ssw);
  const int se1 = spx * 256 + ((sck * 16 + 8) ^ ssw);
  const float* xb = xin + (size_t)b * (KDIM * HWSZ);

  float bi6[6];
  #pragma unroll
  for (int ot = 0; ot < 6; ++ot) {
    const int o = obase + ot * 16 + r16;
    bi6[ot] = bias[o < NOUT ? o : 0];
  }
  const unsigned short* wptr = wbf + (unsigned)(obase + r16) * KDIM + 8 * g;
  const int kxor = (r16 & 7) << 3;

  // prologue: stage unit u0 -> xT[0]
  {
    const int py = (u0 >> 1) & 63, hf = u0 & 1;
    const float* xs = xb + py * 64 + hf * 32 + spx;
    float v[16];
    #pragma unroll
    for (int j = 0; j < 16; ++j) v[j] = xs[(size_t)(sck * 16 + j) * HWSZ];
    union { i32x4 q; unsigned short us[8]; } p0, p1;
    #pragma unroll
    for (int j = 0; j < 8; ++j) { p0.us[j] = f2bf(v[j]); p1.us[j] = f2bf(v[8 + j]); }
    *reinterpret_cast<i32x4*>(&xT[0][se0]) = p0.q;
    *reinterpret_cast<i32x4*>(&xT[0][se1]) = p1.q;
  }
  bar_lds();

  #pragma unroll 1
  for (int i = 0; i < UPB1; ++i) {
    const int u  = u0 + i;
    const int py = (u >> 1) & 63, hf = u & 1;

    // ---- issue next unit's X loads early (fly under GEMM + stores) ----
    float pf[16];
    if (i + 1 < UPB1) {
      const int un = u + 1;
      const int pyn = (un >> 1) & 63, hfn = un & 1;
      const float* xs = xb + pyn * 64 + hfn * 32 + spx;
      #pragma unroll
      for (int j = 0; j < 16; ++j) pf[j] = xs[(size_t)(sck * 16 + j) * HWSZ];
    }

    // ---- GEMM: 32px x 768o; A=X(px), B=W(o); k-permutation cancels ----
    f32x4 acc[6][2];
    #pragma unroll
    for (int ot = 0; ot < 6; ++ot) {
      acc[ot][0] = f32x4{0.f, 0.f, 0.f, 0.f};
      acc[ot][1] = f32x4{0.f, 0.f, 0.f, 0.f};
    }
    const unsigned short* xbuf = &xT[i & 1][0];
    #pragma unroll
    for (int kk = 0; kk < 8; ++kk) {
      const int ke = (kk * 32 + 8 * g) ^ kxor;
      bf16x8 x0 = __builtin_bit_cast(bf16x8,
          *reinterpret_cast<const i32x4*>(&xbuf[r16 * 256 + ke]));
      bf16x8 x1 = __builtin_bit_cast(bf16x8,
          *reinterpret_cast<const i32x4*>(&xbuf[(16 + r16) * 256 + ke]));
      #pragma unroll
      for (int ot = 0; ot < 6; ++ot) {
        bf16x8 w = __builtin_bit_cast(bf16x8,
            *reinterpret_cast<const i32x4*>(wptr + ot * (16 * KDIM) + kk * 32));
        acc[ot][0] = __builtin_amdgcn_mfma_f32_16x16x32_bf16(x0, w, acc[ot][0], 0, 0, 0);
        acc[ot][1] = __builtin_amdgcn_mfma_f32_16x16x32_bf16(x1, w, acc[ot][1], 0, 0, 0);
      }
    }

    // ---- epilogue: bias + bf16 pack + direct store to t[b][o][4096] ----
    // D: col=r16 -> o, row=4g+r -> px = pt*16 + 4g + r. 8B store per (ot,pt).
    #pragma unroll
    for (int ot = 0; ot < 6; ++ot) {
      const int o = obase + ot * 16 + r16;
      unsigned short* tr = t + (size_t)(b * NOUTP + o) * HWSZ + py * 64 + hf * 32;
      #pragma unroll
      for (int pt = 0; pt < 2; ++pt) {
        u16x4 pk = { f2bf(acc[ot][pt].x + bi6[ot]), f2bf(acc[ot][pt].y + bi6[ot]),
                     f2bf(acc[ot][pt].z + bi6[ot]), f2bf(acc[ot][pt].w + bi6[ot]) };
        *reinterpret_cast<u16x4*>(tr + pt * 16 + 4 * g) = pk;
      }
    }

    // ---- write-late: prefetched X -> bf16 -> other xT buffer ----
    if (i + 1 < UPB1) {
      union { i32x4 q; unsigned short us[8]; } p0, p1;
      #pragma unroll
      for (int j = 0; j < 8; ++j) { p0.us[j] = f2bf(pf[j]); p1.us[j] = f2bf(pf[8 + j]); }
      *reinterpret_cast<i32x4*>(&xT[(i + 1) & 1][se0]) = p0.q;
      *reinterpret_cast<i32x4*>(&xT[(i + 1) & 1][se1]) = p1.q;
    }
    bar_lds();
  }
}

// ================= K2 v2: decode + transpose, pure streaming =================
// block = (b, a, 64-px chunk): LDS 21.76 KB -> 7 blocks/CU (28 waves), 9216 blocks.
// Stage: read t[85ch][64px] bf16 with 16B loads, decode (shifts only, y uniform
// per chunk), write f32 lds[px][ch]. Copy-out: 1360 dense dwordx4.
__global__ __launch_bounds__(256) void k2_decode(
    const unsigned short* __restrict__ t,
    float* __restrict__ out)
{
  __shared__ __align__(16) float lds[64 * 85];   // 21760 B

  const int tid   = threadIdx.x;
  const int chunk = blockIdx.x & 63;             // 64-px chunk = one y-row
  const int ba    = blockIdx.x >> 6;             // b*9 + a
  const int a     = ba % 9;
  const int b9    = ba / 9;
  const int hw0   = chunk << 6;
  const float aw  = c_AW[a], ah = c_AH[a];
  const float yv  = (float)chunk * 16.0f;

  const unsigned short* tb = t + (size_t)(b9 * NOUTP + a * 85) * HWSZ + hw0;

  #pragma unroll 1
  for (int e8 = tid; e8 < 680; e8 += 256) {      // 85 ch-rows x 8 px-octets
    const int ch  = e8 >> 3;
    const int px0 = (e8 & 7) << 3;
    const u16x8 raw = *reinterpret_cast<const u16x8*>(tb + (size_t)ch * HWSZ + px0);
    #pragma unroll
    for (int j = 0; j < 8; ++j) {
      const float v = bf2f(raw[j]);
      float val;
      if (ch >= 4)      val = sigf(v);
      else if (ch == 0) val = (sigf(v) - 0.5f) * aw + (float)(px0 + j) * 16.0f;
      else if (ch == 1) val = (sigf(v) - 0.5f) * ah + yv;
      else if (ch == 2) val = __expf(v) * aw;
      else              val = __expf(v) * ah;
      lds[(px0 + j) * 85 + ch] = val;
    }
  }
  bar_lds();

  float* ob = out + ((size_t)ba * HWSZ + hw0) * 85;
  #pragma unroll 1
  for (int q = tid; q < 1360; q += 256)
    *reinterpret_cast<f32x4*>(ob + q * 4) = *reinterpret_cast<const f32x4*>(lds + q * 4);
}

// ================= FALLBACK (round-6 fused kernel) =================
__global__ __launch_bounds__(512) void yolo_fused(
    const float* __restrict__ xin,
    const unsigned short* __restrict__ wbf,
    const float* __restrict__ bias,
    float* __restrict__ out)
{
  __shared__ __align__(16) char smem[3 * 2720 * 4];
  unsigned short* xT  = reinterpret_cast<unsigned short*>(smem);
  float*          stg = reinterpret_cast<float*>(smem);

  const int bid  = blockIdx.x;
  const int ph   = bid & 1;
  const int pc   = (bid >> 1) & 63;
  const int b    = bid >> 7;
  const int tid  = threadIdx.x;
  const int lane = tid & 63;
  const int wv   = tid >> 6;

  {
    const int px     = tid & 31;
    const int c0base = (tid >> 5) << 3;
    const float* xsrc = xin + (size_t)b * KDIM * HWSZ + pc * 64 + ph * 32 + px;
    const int sw = (px & 7) << 3;
    #pragma unroll
    for (int i = 0; i < 2; ++i) {
      const int c0 = c0base + 128 * i;
      float v[8];
      #pragma unroll
      for (int j = 0; j < 8; ++j) v[j] = xsrc[(size_t)(c0 + j) * HWSZ];
      union { i32x4 q; unsigned short us[8]; } pk;
      #pragma unroll
      for (int j = 0; j < 8; ++j) pk.us[j] = f2bf(v[j]);
      *reinterpret_cast<i32x4*>(&xT[(px << 8) + (c0 ^ sw)]) = pk.q;
    }
  }
  bar_lds();

  const int g = lane >> 4, r16 = lane & 15, obase = wv * 96;
  f32x4 acc[6][2];
  #pragma unroll
  for (int ot = 0; ot < 6; ++ot) { acc[ot][0] = f32x4{0,0,0,0}; acc[ot][1] = f32x4{0,0,0,0}; }

  const unsigned short* wptr = wbf + (unsigned)(obase + r16) * KDIM + 8 * g;
  const int xb0 = (r16 << 8), xb1 = ((16 + r16) << 8), sw0 = (r16 & 7) << 3;

  #pragma unroll
  for (int kk = 0; kk < 8; ++kk) {
    const int ke = (kk * 32 + 8 * g) ^ sw0;
    bf16x8 x0 = __builtin_bit_cast(bf16x8, *reinterpret_cast<const i32x4*>(&xT[xb0 + ke]));
    bf16x8 x1 = __builtin_bit_cast(bf16x8, *reinterpret_cast<const i32x4*>(&xT[xb1 + ke]));
    #pragma unroll
    for (int ot = 0; ot < 6; ++ot) {
      bf16x8 w = __builtin_bit_cast(bf16x8,
          *reinterpret_cast<const i32x4*>(wptr + ot * 16 * KDIM + kk * 32));
      acc[ot][0] = __builtin_amdgcn_mfma_f32_16x16x32_bf16(x0, w, acc[ot][0], 0, 0, 0);
      acc[ot][1] = __builtin_amdgcn_mfma_f32_16x16x32_bf16(x1, w, acc[ot][1], 0, 0, 0);
    }
  }
  bar_lds();

  float bi[6];
  #pragma unroll
  for (int ot = 0; ot < 6; ++ot) {
    const int o = obase + ot * 16 + r16;
    bi[ot] = bias[o < NOUT ? o : 0];
  }
  const float ys = (float)pc * 16.0f, xs0 = (float)(ph * 32) * 16.0f;

  #pragma unroll 1
  for (int t3 = 0; t3 < 3; ++t3) {
    const int alo = 3 * t3;
    #pragma unroll
    for (int ot = 0; ot < 6; ++ot) {
      const int o = obase + ot * 16 + r16;
      const int a = o / 85;
      if (a >= alo && a < alo + 3) {
        const int ch = o - a * 85;
        const float aw = c_AW[a], ah = c_AH[a];
        float* sdst = stg + (a - alo) * 2720 + ch;
        #pragma unroll
        for (int pt = 0; pt < 2; ++pt) {
          #pragma unroll
          for (int r = 0; r < 4; ++r) {
            const int   pxl = pt * 16 + g * 4 + r;
            const float tv  = acc[ot][pt][r] + bi[ot];
            float val;
            if (ch >= 4)      val = sigf(tv);
            else if (ch == 0) val = (sigf(tv) - 0.5f) * aw + xs0 + (float)pxl * 16.0f;
            else if (ch == 1) val = (sigf(tv) - 0.5f) * ah + ys;
            else if (ch == 2) val = __expf(tv) * aw;
            else              val = __expf(tv) * ah;
            sdst[pxl * 85] = val;
          }
        }
      }
    }
    bar_lds();
    #pragma unroll 1
    for (int q = tid; q < 2040; q += 512) {
      const int al = (q >= 1360) ? 2 : (q >= 680 ? 1 : 0);
      const int a  = alo + al;
      const f32x4 v = *reinterpret_cast<const f32x4*>(stg + q * 4);
      const unsigned dstdw = ((unsigned)(b * 9 + a) * HWSZ + (unsigned)(pc * 64 + ph * 32)) * 85u
                           + (unsigned)(q - al * 680) * 4u;
      *reinterpret_cast<f32x4*>(out + dstdw) = v;
    }
    bar_lds();
  }
}

extern "C" void kernel_launch(void* const* d_in, const int* in_sizes, int n_in,
                              void* d_out, int out_size, void* d_ws, size_t ws_size,
                              hipStream_t stream) {
  const float* xin = (const float*)d_in[0];
  const float* cw  = (const float*)d_in[1];
  const float* cb  = (const float*)d_in[2];
  float* out = (float*)d_out;

  if (ws_size >= TBYTES + 393216) {
    unsigned short* t   = (unsigned short*)d_ws;
    unsigned short* wbf = (unsigned short*)((char*)d_ws + TBYTES);
    prep_w<<<dim3((NOUTP * KDIM / 4) / 256), dim3(256), 0, stream>>>(cw, wbf);
    k1_gemm<<<dim3(2048 / UPB1), dim3(512), 0, stream>>>(xin, wbf, cb, t);
    k2_decode<<<dim3(16 * 9 * 64), dim3(256), 0, stream>>>(t, out);
  } else {
    unsigned short* wbf = (unsigned short*)d_ws;   // 393216 B
    prep_w<<<dim3((NOUTP * KDIM / 4) / 256), dim3(256), 0, stream>>>(cw, wbf);
    yolo_fused<<<dim3(16 * 64 * 2), dim3(512), 0, stream>>>(xin, wbf, cb, out);
  }
}

// Round 9
// 181.813 us; speedup vs baseline: 2.8571x; 2.8571x over previous
//
#include <hip/hip_runtime.h>

typedef __attribute__((ext_vector_type(8))) short bf16x8;
typedef __attribute__((ext_vector_type(4))) float f32x4;
typedef __attribute__((ext_vector_type(4))) int i32x4;
typedef __attribute__((ext_vector_type(4))) unsigned short u16x4;
typedef __attribute__((ext_vector_type(8))) unsigned short u16x8;

#define KDIM 256
#define HWSZ 4096
#define NOUT 765
#define NOUTP 768
#define TBYTES ((size_t)16 * NOUTP * HWSZ * 2)   // 100,663,296 B bf16 t-buffer

// Anchors in PIXEL units: w_a = ANCHORS/16 (grid units) and every use multiplies
// by STRIDE=16, so pixel units are exact. Index 9 = dummy for padded o.
__constant__ float c_AW[10] = {10.f,16.f,33.f,30.f,62.f,59.f,116.f,156.f,373.f,0.f};
__constant__ float c_AH[10] = {13.f,30.f,23.f,61.f,45.f,119.f,90.f,198.f,326.f,0.f};

__device__ __forceinline__ unsigned short f2bf(float f) {
  unsigned u = __builtin_bit_cast(unsigned, f);
  u += 0x7fffu + ((u >> 16) & 1u);   // RNE
  return (unsigned short)(u >> 16);
}
__device__ __forceinline__ float bf2f(unsigned short h) {
  return __builtin_bit_cast(float, ((unsigned)h) << 16);
}
__device__ __forceinline__ float sigf(float t) {
  return 1.0f / (1.0f + __expf(-t));
}

// LDS-hazard-only barrier (validated rounds 5-8: correct, absmax stable).
// Does NOT drain vmcnt: staging loads + t/out store streams stay in flight.
__device__ __forceinline__ void bar_lds() {
  asm volatile("s_waitcnt lgkmcnt(0)" ::: "memory");
  __builtin_amdgcn_s_barrier();
  __builtin_amdgcn_sched_barrier(0);
}

// ---- prep: conv_w (765x256 f32) -> padded bf16 (768x256), rows 765..767 = 0
__global__ void prep_w(const float* __restrict__ cw, unsigned short* __restrict__ wbf) {
  int e = (blockIdx.x * 256 + threadIdx.x) * 4;
  int o = e >> 8, col = e & 255;
  f32x4 v = {0.f, 0.f, 0.f, 0.f};
  if (o < NOUT) v = *reinterpret_cast<const f32x4*>(cw + o * KDIM + col);
  u16x4 u = { f2bf(v.x), f2bf(v.y), f2bf(v.z), f2bf(v.w) };
  *reinterpret_cast<u16x4*>(wbf + e) = u;
}

// ================= K1 v3: plain GEMM, r4-proven register envelope =================
// 2048 blocks; block = (b, half-row) = 32 px x all 768 o. 8 waves, wave wv owns
// o in [96wv,96wv+96): acc[6][2] = 48 regs; total 112 VGPR measured (r4), zero
// spill, 2 blocks/CU -> stage/GEMM/store phases overlap across blocks.
// NO register prefetch across the MFMA loop (r8: pf[16] -> 128-cap -> spill).
// Epilogue: bias + bf16 pack + direct 8B stores to t[b][o][4096]; the 4 px-quads
// per o-row tile one dense 64B segment per block.
__global__ __launch_bounds__(512) void k1_gemm(
    const float* __restrict__ xin,
    const unsigned short* __restrict__ wbf,
    const float* __restrict__ bias,
    unsigned short* __restrict__ t)
{
  __shared__ __align__(16) unsigned short xT[32 * 256];   // 16 KB, k-bits 3..5 XOR-swizzled by px&7

  const int tid  = threadIdx.x;
  const int lane = tid & 63;
  const int wv   = tid >> 6;
  const int g    = lane >> 4;
  const int r16  = lane & 15;
  const int obase = wv * 96;

  const int bid = blockIdx.x;           // 2048 = 16 b x 64 py x 2 hf
  const int hf  = bid & 1;
  const int py  = (bid >> 1) & 63;
  const int b   = bid >> 7;

  // ---------- stage X^T (f32 -> bf16, swizzled): thread = (px, 16 c's) ----------
  {
    const int spx = tid & 31;
    const int sck = tid >> 5;                    // 0..15
    const int ssw = (spx & 7) << 3;
    const float* xs = xin + (size_t)b * (KDIM * HWSZ) + py * 64 + hf * 32 + spx;
    float v[16];
    #pragma unroll
    for (int j = 0; j < 16; ++j) v[j] = xs[(size_t)(sck * 16 + j) * HWSZ];
    union { i32x4 q; unsigned short us[8]; } p0, p1;
    #pragma unroll
    for (int j = 0; j < 8; ++j) { p0.us[j] = f2bf(v[j]); p1.us[j] = f2bf(v[8 + j]); }
    *reinterpret_cast<i32x4*>(&xT[spx * 256 + ((sck * 16) ^ ssw)]) = p0.q;
    *reinterpret_cast<i32x4*>(&xT[spx * 256 + ((sck * 16 + 8) ^ ssw)]) = p1.q;
  }
  bar_lds();

  // ---------- GEMM: 32px x 768o; A=X(px), B=W(o); k-permutation cancels ----------
  f32x4 acc[6][2];
  #pragma unroll
  for (int ot = 0; ot < 6; ++ot) {
    acc[ot][0] = f32x4{0.f, 0.f, 0.f, 0.f};
    acc[ot][1] = f32x4{0.f, 0.f, 0.f, 0.f};
  }
  const unsigned short* wptr = wbf + (unsigned)(obase + r16) * KDIM + 8 * g;
  const int kxor = (r16 & 7) << 3;

  #pragma unroll
  for (int kk = 0; kk < 8; ++kk) {
    const int ke = (kk * 32 + 8 * g) ^ kxor;
    bf16x8 x0 = __builtin_bit_cast(bf16x8,
        *reinterpret_cast<const i32x4*>(&xT[r16 * 256 + ke]));
    bf16x8 x1 = __builtin_bit_cast(bf16x8,
        *reinterpret_cast<const i32x4*>(&xT[(16 + r16) * 256 + ke]));
    #pragma unroll
    for (int ot = 0; ot < 6; ++ot) {
      bf16x8 w = __builtin_bit_cast(bf16x8,
          *reinterpret_cast<const i32x4*>(wptr + ot * (16 * KDIM) + kk * 32));
      acc[ot][0] = __builtin_amdgcn_mfma_f32_16x16x32_bf16(x0, w, acc[ot][0], 0, 0, 0);
      acc[ot][1] = __builtin_amdgcn_mfma_f32_16x16x32_bf16(x1, w, acc[ot][1], 0, 0, 0);
    }
  }

  // ---------- epilogue: bias + bf16 pack + direct store to t[b][o][4096] ----------
  // D: col=r16 -> o, row=4g+r -> px = pt*16 + 4g + r. 8B store per (ot,pt).
  #pragma unroll
  for (int ot = 0; ot < 6; ++ot) {
    const int o = obase + ot * 16 + r16;
    const float bi = bias[o < NOUT ? o : 0];
    unsigned short* tr = t + (size_t)(b * NOUTP + o) * HWSZ + py * 64 + hf * 32;
    #pragma unroll
    for (int pt = 0; pt < 2; ++pt) {
      u16x4 pk = { f2bf(acc[ot][pt].x + bi), f2bf(acc[ot][pt].y + bi),
                   f2bf(acc[ot][pt].z + bi), f2bf(acc[ot][pt].w + bi) };
      *reinterpret_cast<u16x4*>(tr + pt * 16 + 4 * g) = pk;
    }
  }
}

// ================= K2 v2: decode + transpose (r8, measured ~19-30us) =================
// block = (b, a, 64-px chunk): LDS 21.76 KB -> 7 blocks/CU, 9216 blocks. t reads
// hit L3 (t fits in 256MB Infinity Cache, freshly written by k1).
__global__ __launch_bounds__(256) void k2_decode(
    const unsigned short* __restrict__ t,
    float* __restrict__ out)
{
  __shared__ __align__(16) float lds[64 * 85];   // 21760 B

  const int tid   = threadIdx.x;
  const int chunk = blockIdx.x & 63;             // 64-px chunk = one y-row
  const int ba    = blockIdx.x >> 6;             // b*9 + a
  const int a     = ba % 9;
  const int b9    = ba / 9;
  const int hw0   = chunk << 6;
  const float aw  = c_AW[a], ah = c_AH[a];
  const float yv  = (float)chunk * 16.0f;

  const unsigned short* tb = t + (size_t)(b9 * NOUTP + a * 85) * HWSZ + hw0;

  #pragma unroll 1
  for (int e8 = tid; e8 < 680; e8 += 256) {      // 85 ch-rows x 8 px-octets
    const int ch  = e8 >> 3;
    const int px0 = (e8 & 7) << 3;
    const u16x8 raw = *reinterpret_cast<const u16x8*>(tb + (size_t)ch * HWSZ + px0);
    #pragma unroll
    for (int j = 0; j < 8; ++j) {
      const float v = bf2f(raw[j]);
      float val;
      if (ch >= 4)      val = sigf(v);
      else if (ch == 0) val = (sigf(v) - 0.5f) * aw + (float)(px0 + j) * 16.0f;
      else if (ch == 1) val = (sigf(v) - 0.5f) * ah + yv;
      else if (ch == 2) val = __expf(v) * aw;
      else              val = __expf(v) * ah;
      lds[(px0 + j) * 85 + ch] = val;
    }
  }
  bar_lds();

  float* ob = out + ((size_t)ba * HWSZ + hw0) * 85;
  #pragma unroll 1
  for (int q = tid; q < 1360; q += 256)
    *reinterpret_cast<f32x4*>(ob + q * 4) = *reinterpret_cast<const f32x4*>(lds + q * 4);
}

// ================= FALLBACK (round-6 fused kernel) =================
__global__ __launch_bounds__(512) void yolo_fused(
    const float* __restrict__ xin,
    const unsigned short* __restrict__ wbf,
    const float* __restrict__ bias,
    float* __restrict__ out)
{
  __shared__ __align__(16) char smem[3 * 2720 * 4];
  unsigned short* xT  = reinterpret_cast<unsigned short*>(smem);
  float*          stg = reinterpret_cast<float*>(smem);

  const int bid  = blockIdx.x;
  const int ph   = bid & 1;
  const int pc   = (bid >> 1) & 63;
  const int b    = bid >> 7;
  const int tid  = threadIdx.x;
  const int lane = tid & 63;
  const int wv   = tid >> 6;

  {
    const int px     = tid & 31;
    const int c0base = (tid >> 5) << 3;
    const float* xsrc = xin + (size_t)b * KDIM * HWSZ + pc * 64 + ph * 32 + px;
    const int sw = (px & 7) << 3;
    #pragma unroll
    for (int i = 0; i < 2; ++i) {
      const int c0 = c0base + 128 * i;
      float v[8];
      #pragma unroll
      for (int j = 0; j < 8; ++j) v[j] = xsrc[(size_t)(c0 + j) * HWSZ];
      union { i32x4 q; unsigned short us[8]; } pk;
      #pragma unroll
      for (int j = 0; j < 8; ++j) pk.us[j] = f2bf(v[j]);
      *reinterpret_cast<i32x4*>(&xT[(px << 8) + (c0 ^ sw)]) = pk.q;
    }
  }
  bar_lds();

  const int g = lane >> 4, r16 = lane & 15, obase = wv * 96;
  f32x4 acc[6][2];
  #pragma unroll
  for (int ot = 0; ot < 6; ++ot) { acc[ot][0] = f32x4{0,0,0,0}; acc[ot][1] = f32x4{0,0,0,0}; }

  const unsigned short* wptr = wbf + (unsigned)(obase + r16) * KDIM + 8 * g;
  const int xb0 = (r16 << 8), xb1 = ((16 + r16) << 8), sw0 = (r16 & 7) << 3;

  #pragma unroll
  for (int kk = 0; kk < 8; ++kk) {
    const int ke = (kk * 32 + 8 * g) ^ sw0;
    bf16x8 x0 = __builtin_bit_cast(bf16x8, *reinterpret_cast<const i32x4*>(&xT[xb0 + ke]));
    bf16x8 x1 = __builtin_bit_cast(bf16x8, *reinterpret_cast<const i32x4*>(&xT[xb1 + ke]));
    #pragma unroll
    for (int ot = 0; ot < 6; ++ot) {
      bf16x8 w = __builtin_bit_cast(bf16x8,
          *reinterpret_cast<const i32x4*>(wptr + ot * 16 * KDIM + kk * 32));
      acc[ot][0] = __builtin_amdgcn_mfma_f32_16x16x32_bf16(x0, w, acc[ot][0], 0, 0, 0);
      acc[ot][1] = __builtin_amdgcn_mfma_f32_16x16x32_bf16(x1, w, acc[ot][1], 0, 0, 0);
    }
  }
  bar_lds();

  float bi[6];
  #pragma unroll
  for (int ot = 0; ot < 6; ++ot) {
    const int o = obase + ot * 16 + r16;
    bi[ot] = bias[o < NOUT ? o : 0];
  }
  const float ys = (float)pc * 16.0f, xs0 = (float)(ph * 32) * 16.0f;

  #pragma unroll 1
  for (int t3 = 0; t3 < 3; ++t3) {
    const int alo = 3 * t3;
    #pragma unroll
    for (int ot = 0; ot < 6; ++ot) {
      const int o = obase + ot * 16 + r16;
      const int a = o / 85;
      if (a >= alo && a < alo + 3) {
        const int ch = o - a * 85;
        const float aw = c_AW[a], ah = c_AH[a];
        float* sdst = stg + (a - alo) * 2720 + ch;
        #pragma unroll
        for (int pt = 0; pt < 2; ++pt) {
          #pragma unroll
          for (int r = 0; r < 4; ++r) {
            const int   pxl = pt * 16 + g * 4 + r;
            const float tv  = acc[ot][pt][r] + bi[ot];
            float val;
            if (ch >= 4)      val = sigf(tv);
            else if (ch == 0) val = (sigf(tv) - 0.5f) * aw + xs0 + (float)pxl * 16.0f;
            else if (ch == 1) val = (sigf(tv) - 0.5f) * ah + ys;
            else if (ch == 2) val = __expf(tv) * aw;
            else              val = __expf(tv) * ah;
            sdst[pxl * 85] = val;
          }
        }
      }
    }
    bar_lds();
    #pragma unroll 1
    for (int q = tid; q < 2040; q += 512) {
      const int al = (q >= 1360) ? 2 : (q >= 680 ? 1 : 0);
      const int a  = alo + al;
      const f32x4 v = *reinterpret_cast<const f32x4*>(stg + q * 4);
      const unsigned dstdw = ((unsigned)(b * 9 + a) * HWSZ + (unsigned)(pc * 64 + ph * 32)) * 85u
                           + (unsigned)(q - al * 680) * 4u;
      *reinterpret_cast<f32x4*>(out + dstdw) = v;
    }
    bar_lds();
  }
}

extern "C" void kernel_launch(void* const* d_in, const int* in_sizes, int n_in,
                              void* d_out, int out_size, void* d_ws, size_t ws_size,
                              hipStream_t stream) {
  const float* xin = (const float*)d_in[0];
  const float* cw  = (const float*)d_in[1];
  const float* cb  = (const float*)d_in[2];
  float* out = (float*)d_out;

  if (ws_size >= TBYTES + 393216) {
    unsigned short* t   = (unsigned short*)d_ws;
    unsigned short* wbf = (unsigned short*)((char*)d_ws + TBYTES);
    prep_w<<<dim3((NOUTP * KDIM / 4) / 256), dim3(256), 0, stream>>>(cw, wbf);
    k1_gemm<<<dim3(2048), dim3(512), 0, stream>>>(xin, wbf, cb, t);
    k2_decode<<<dim3(16 * 9 * 64), dim3(256), 0, stream>>>(t, out);
  } else {
    unsigned short* wbf = (unsigned short*)d_ws;   // 393216 B
    prep_w<<<dim3((NOUTP * KDIM / 4) / 256), dim3(256), 0, stream>>>(cw, wbf);
    yolo_fused<<<dim3(16 * 64 * 2), dim3(512), 0, stream>>>(xin, wbf, cb, out);
  }
}